// Round 9
// baseline (88.831 us; speedup 1.0000x reference)
//
#include <hip/hip_runtime.h>

// s = sum_{b,i,j} X[b,i] W[i,j] G[b,i/128,j/128]; out = s^2.
// Factor over j:  s = sum_{i,jb} Wsum[i,jb] * H[i,jb],
//   Wsum[i,jb] = sum_{c<128} W[i, jb*128+c]
//   H[i,jb]    = sum_b X[b,i] * G[b, i/128, jb]
// R8 post-mortem: hipLaunchCooperativeKernel silently no-ops under graph
// capture (out stayed 0) -> grid.sync fusion impossible; back to 3 kernels.
// K1 (this round): 2 KB/wave (two independent float4 chains) -> half the
//   waves of R7, 2x MLP per wave. WsumT[jb][i] transposed for k2 coalescing.
// K2: R7 byte-identical (passed, ~fast): LDS-staged G, uniform ds_read
//   broadcasts, pinned wv, no atomics (R4: cross-XCD RMW ping-pong ~19ns).
// K3: 1-block finish.

#define B_DIM 1536
#define DI    1536
#define DO    4608
#define NI    12
#define NJ    36
#define GROW  (NI * NJ)            // 432 floats per G batch-row
#define BPW   8                    // b's per wave in kernel 2
#define K2_WAVES  (24 * (B_DIM / BPW))   // 24 i-blocks x 192 b-ranges = 4608
#define K2_BLOCKS (K2_WAVES / 4)         // 1152

// ---- Kernel 1: WsumT[jb][i]; wave covers W[i, q*512 .. q*512+512) ----
// Two independent float4 loads per lane (2 KB/wave): load0 -> jb {4q, 4q+1}
// (lane halves), load1 -> jb {4q+2, 4q+3}. 13824 waves = 3456 blocks.
__global__ __launch_bounds__(256) void wsum_kernel(const float* __restrict__ W,
                                                   float* __restrict__ WsumT) {
    int g    = blockIdx.x * 4 + (threadIdx.x >> 6);  // wave id, [0, 13824)
    int lane = threadIdx.x & 63;
    int i = g / 9;           // W row
    int q = g - i * 9;       // 512-float chunk: jb = 4q .. 4q+3
    const float4* p = (const float4*)(W + (size_t)i * DO + (size_t)q * 512);
    float4 v0 = p[lane];           // lanes 0-31: jb 4q;   32-63: jb 4q+1
    float4 v1 = p[lane + 64];      // lanes 0-31: jb 4q+2; 32-63: jb 4q+3
    float s0 = (v0.x + v0.y) + (v0.z + v0.w);
    float s1 = (v1.x + v1.y) + (v1.z + v1.w);
    #pragma unroll
    for (int off = 16; off > 0; off >>= 1) {   // two independent 32-lane trees
        s0 += __shfl_xor(s0, off, 64);
        s1 += __shfl_xor(s1, off, 64);
    }
    int half = lane >> 5;          // 0 or 1
    if ((lane & 31) == 0) {
        WsumT[(size_t)(4 * q + half)     * DI + i] = s0;
        WsumT[(size_t)(4 * q + 2 + half) * DI + i] = s1;
    }
}

// ---- Kernel 2: s += x * dot36(wv, G_row); G via LDS broadcast (R7) ----
__global__ __launch_bounds__(256, 4) void gated_kernel(const float* __restrict__ X,
                                                       const float* __restrict__ G,
                                                       const float* __restrict__ WsumT,
                                                       float* __restrict__ partials) {
    __shared__ float4 gs4[BPW * 72 / 4];   // 8 b x 2 ib-rows x 36 = 2304 B
    __shared__ float red[4];
    float* gs = (float*)gs4;

    const int t     = threadIdx.x;
    const int w     = t >> 6;
    const int lane  = t & 63;
    const int wave0 = blockIdx.x * 4;
    const int brng  = wave0 / 24;          // block-uniform (4 | 24)
    const int a     = (wave0 % 24) >> 2;   // block's iblk quad -> ib pair {2a,2a+1}
    const int b0    = brng * BPW;
    const int iblk  = (wave0 % 24) + w;
    const int i     = iblk * 64 + lane;
    const int d     = w >> 1;              // which staged ib row this wave uses

    // Cooperative stage of G slice [b0..b0+7] x [2a..2a+1] x [0..35]:
    // contiguous 72-float runs per b -> coalesced; full MLP, one drain.
    for (int e = t; e < BPW * 72; e += 256) {
        int b = e / 72, r = e - b * 72;
        gs[e] = G[(size_t)(b0 + b) * GROW + (size_t)(2 * a) * NJ + r];
    }

    // Loop-invariant Wsum slice, coalesced: wv[k] = WsumT[k][i].
    float wv[NJ];
    #pragma unroll
    for (int k = 0; k < NJ; ++k) wv[k] = WsumT[(size_t)k * DI + i];
    #pragma unroll
    for (int k = 0; k < NJ; ++k) asm("" : "+v"(wv[k]));   // keep resident

    __syncthreads();

    const float* xp = X + (size_t)b0 * DI + i;     // coalesced, lane<->i
    float s = 0.f;
    #pragma unroll
    for (int bb = 0; bb < BPW; ++bb) {
        float x = xp[(size_t)bb * DI];
        const float4* gp = (const float4*)(gs + bb * 72 + d * 36);  // uniform addr
        float d0 = 0.f, d1 = 0.f;
        #pragma unroll
        for (int k4 = 0; k4 < 9; ++k4) {
            float4 gv = gp[k4];                    // ds_read_b128 broadcast
            d0 = fmaf(wv[4*k4+0], gv.x, d0);
            d1 = fmaf(wv[4*k4+1], gv.y, d1);
            d0 = fmaf(wv[4*k4+2], gv.z, d0);
            d1 = fmaf(wv[4*k4+3], gv.w, d1);
        }
        s = fmaf(x, d0 + d1, s);
    }

    #pragma unroll
    for (int off = 1; off < 64; off <<= 1) s += __shfl_xor(s, off, 64);
    if (lane == 0) red[w] = s;
    __syncthreads();
    if (t == 0)
        partials[blockIdx.x] = (red[0] + red[1]) + (red[2] + red[3]);
}

// ---- Kernel 3: final reduce + square (1 block) ----
__global__ __launch_bounds__(256) void finish_kernel(const float* __restrict__ partials,
                                                     float* __restrict__ out) {
    __shared__ float red[4];
    const int t = threadIdx.x;
    float s = 0.f;
    for (int e = t; e < K2_BLOCKS; e += 256) s += partials[e];
    #pragma unroll
    for (int off = 1; off < 64; off <<= 1) s += __shfl_xor(s, off, 64);
    const int w = t >> 6, lane = t & 63;
    if (lane == 0) red[w] = s;
    __syncthreads();
    if (t == 0) {
        float tot = (red[0] + red[1]) + (red[2] + red[3]);
        out[0] = tot * tot;
    }
}

extern "C" void kernel_launch(void* const* d_in, const int* in_sizes, int n_in,
                              void* d_out, int out_size, void* d_ws, size_t ws_size,
                              hipStream_t stream) {
    const float* X = (const float*)d_in[0];  // [1536,1536]
    const float* W = (const float*)d_in[1];  // [1536,4608]
    const float* G = (const float*)d_in[2];  // [1536,12,36]
    float* out = (float*)d_out;

    float* WsumT    = (float*)d_ws;                 // 55296 floats, [36][1536]
    float* partials = WsumT + (size_t)NJ * DI;      // 1152 floats

    // Kernel 1: 13824 waves = 3456 blocks x 4 waves (2 KB of W per wave).
    wsum_kernel<<<(DI * 9) / 4, 256, 0, stream>>>(W, WsumT);
    // Kernel 2: 1152 blocks x 256 threads -> plain partials (no atomics).
    gated_kernel<<<K2_BLOCKS, 256, 0, stream>>>(X, G, WsumT, partials);
    // Kernel 3: single block reduces 1152 partials and squares.
    finish_kernel<<<1, 256, 0, stream>>>(partials, out);
}